// Round 17
// baseline (93.266 us; speedup 1.0000x reference)
//
#include <hip/hip_runtime.h>
#include <math.h>

#define S_LEN 2048
#define BATCH 4
#define DMODEL 1024
#define HDIM 64
#define NROWS (BATCH * S_LEN)   // 8192

typedef __attribute__((ext_vector_type(8))) short bf16x8;
typedef __attribute__((ext_vector_type(4))) float f32x4;

__device__ inline ushort f2bf(float f) {
    union { float f; uint u; } v{f};
    uint r = v.u + 0x7fffu + ((v.u >> 16) & 1u);   // RNE
    return (ushort)(r >> 16);
}

__device__ inline bf16x8 cvt8(float4 a, float4 b) {
    bf16x8 r;
    r[0] = (short)f2bf(a.x); r[1] = (short)f2bf(a.y);
    r[2] = (short)f2bf(a.z); r[3] = (short)f2bf(a.w);
    r[4] = (short)f2bf(b.x); r[5] = (short)f2bf(b.y);
    r[6] = (short)f2bf(b.z); r[7] = (short)f2bf(b.w);
    return r;
}

// ---------------------------------------------------------------------------
// transpose_wh: w_h f32 [1024][64] -> whT bf16 [64][1024].  Grid (16, 3).
// ---------------------------------------------------------------------------
__global__ __launch_bounds__(256) void transpose_wh(
    const float* __restrict__ B0, const float* __restrict__ B1, const float* __restrict__ B2,
    ushort* __restrict__ T0, ushort* __restrict__ T1, ushort* __restrict__ T2)
{
    const int z = blockIdx.y;
    const float* B = (z == 0) ? B0 : (z == 1) ? B1 : B2;
    ushort* T      = (z == 0) ? T0 : (z == 1) ? T1 : T2;
    const int kr0 = blockIdx.x * 64;
    __shared__ ushort Ts[64][72];
    const int t = threadIdx.x;

    #pragma unroll
    for (int q = 0; q < 4; ++q) {
        int u   = t * 4 + q;
        int row = u >> 4;
        int c4  = (u & 15) << 2;
        float4 v = *reinterpret_cast<const float4*>(
            B + (size_t)(kr0 + row) * 64 + c4);
        Ts[row][c4 + 0] = f2bf(v.x); Ts[row][c4 + 1] = f2bf(v.y);
        Ts[row][c4 + 2] = f2bf(v.z); Ts[row][c4 + 3] = f2bf(v.w);
    }
    __syncthreads();
    #pragma unroll
    for (int q = 0; q < 2; ++q) {
        int u  = t * 2 + q;
        int h  = u >> 3;
        int k8 = (u & 7) << 3;
        uint4 o;
        uint* ow = reinterpret_cast<uint*>(&o);
        #pragma unroll
        for (int i = 0; i < 4; ++i)
            ow[i] = (uint)Ts[k8 + 2 * i][h] | ((uint)Ts[k8 + 2 * i + 1][h] << 16);
        *reinterpret_cast<uint4*>(T + (size_t)h * 1024 + kr0 + k8) = o;
    }
}

// ---------------------------------------------------------------------------
// fold_wo: WoT[e][j] = sum_h Wo[h*64+j][e]  -> bf16 [1024][64].  Grid 256.
// ---------------------------------------------------------------------------
__global__ __launch_bounds__(256) void fold_wo(const float* __restrict__ Wo,
                                               ushort* __restrict__ WoT)
{
    int idx = blockIdx.x * 256 + threadIdx.x;
    int j = idx >> 10;
    int e = idx & 1023;
    float s = 0.f;
    #pragma unroll
    for (int h = 0; h < 16; ++h)
        s += Wo[(size_t)((h << 6) + j) * 1024 + e];
    WoT[(size_t)e * 64 + j] = f2bf(s);
}

// ---------------------------------------------------------------------------
// prep_direct: WeffT_z[h][d] = (W_z @ w_h_z)^T bf16.  Grid (64, 3).
// ---------------------------------------------------------------------------
__global__ __launch_bounds__(256) void prep_direct(
    const float* __restrict__ A0, const float* __restrict__ A1, const float* __restrict__ A2,
    const ushort* __restrict__ W0, const ushort* __restrict__ W1, const ushort* __restrict__ W2,
    ushort* __restrict__ T0, ushort* __restrict__ T1, ushort* __restrict__ T2)
{
    const int z = blockIdx.y;
    const float* A  = (z == 0) ? A0 : (z == 1) ? A1 : A2;
    const ushort* W = (z == 0) ? W0 : (z == 1) ? W1 : W2;
    ushort* T       = (z == 0) ? T0 : (z == 1) ? T1 : T2;

    __shared__ float Pr[4][16][64];

    const int t    = threadIdx.x;
    const int w    = t >> 6;
    const int lane = t & 63;
    const int lg   = lane >> 4;
    const int lc   = lane & 15;
    const int r0   = blockIdx.x * 16;

    const float*  Ap = A + (size_t)(r0 + lc) * 1024 + (w << 8) + (lg << 3);
    const ushort* Bp = W + (size_t)lc * 1024 + (w << 8) + (lg << 3);

    f32x4 acc[4] = {};
    float4 a0[2], a1[2];
    uint4  bl[2][4];

    #pragma unroll
    for (int d = 0; d < 2; ++d) {
        a0[d] = *reinterpret_cast<const float4*>(Ap + d * 32);
        a1[d] = *reinterpret_cast<const float4*>(Ap + d * 32 + 4);
        #pragma unroll
        for (int n = 0; n < 4; ++n)
            bl[d][n] = *reinterpret_cast<const uint4*>(Bp + n * 16384 + d * 32);
    }

    #pragma unroll
    for (int ks = 0; ks < 8; ++ks) {
        const int d = ks & 1;
        bf16x8 af = cvt8(a0[d], a1[d]);
        bf16x8 bfr[4];
        #pragma unroll
        for (int n = 0; n < 4; ++n)
            bfr[n] = __builtin_bit_cast(bf16x8, bl[d][n]);
        if (ks < 6) {
            a0[d] = *reinterpret_cast<const float4*>(Ap + (ks + 2) * 32);
            a1[d] = *reinterpret_cast<const float4*>(Ap + (ks + 2) * 32 + 4);
            #pragma unroll
            for (int n = 0; n < 4; ++n)
                bl[d][n] = *reinterpret_cast<const uint4*>(Bp + n * 16384 + (ks + 2) * 32);
        }
        #pragma unroll
        for (int n = 0; n < 4; ++n)
            acc[n] = __builtin_amdgcn_mfma_f32_16x16x32_bf16(af, bfr[n], acc[n], 0, 0, 0);
    }

    #pragma unroll
    for (int n = 0; n < 4; ++n)
        #pragma unroll
        for (int reg = 0; reg < 4; ++reg)
            Pr[w][4 * lg + reg][16 * n + lc] = acc[n][reg];
    __syncthreads();

    const int row = t >> 4;
    const int col = (t & 15) << 2;
    float s[4];
    #pragma unroll
    for (int i = 0; i < 4; ++i)
        s[i] = Pr[0][row][col + i] + Pr[1][row][col + i] +
               Pr[2][row][col + i] + Pr[3][row][col + i];
    #pragma unroll
    for (int i = 0; i < 4; ++i)
        T[(size_t)(col + i) * 1024 + r0 + row] = f2bf(s[i]);
}

// ---------------------------------------------------------------------------
// Projections (MFMA, BK=128): Grid (128, 3), 256 thr = 4 waves.
// Change vs R16: K-step 64->128 (halves __syncthreads drains 32->16) and B
// read DIRECT from L2-hot WeffT (no B LDS stage) — the one untried lever on
// the validated R4 structure.  Accumulation order per acc[n] unchanged.
// z==0/1 write qh/kh row-major; z==2 writes vhT transposed (validated R15).
// ---------------------------------------------------------------------------
__global__ __launch_bounds__(256) void proj_mfma(
    const float* __restrict__ A0, const float* __restrict__ A1, const float* __restrict__ A2,
    const ushort* __restrict__ W0, const ushort* __restrict__ W1, const ushort* __restrict__ W2,
    const float* __restrict__ b0, const float* __restrict__ b1, const float* __restrict__ b2,
    ushort* __restrict__ O0, ushort* __restrict__ O1, ushort* __restrict__ O2)
{
    const int z = blockIdx.y;
    const float* A  = (z == 0) ? A0 : (z == 1) ? A1 : A2;
    const ushort* W = (z == 0) ? W0 : (z == 1) ? W1 : W2;
    const float* bias = (z == 0) ? b0 : (z == 1) ? b1 : b2;
    ushort* O       = (z == 0) ? O0 : (z == 1) ? O1 : O2;

    __shared__ ushort As[64][136];   // 64 rows x 128 k bf16, +8 pad (17.4 KB)

    const int t    = threadIdx.x;
    const int w    = t >> 6;
    const int lane = t & 63;
    const int lg   = lane >> 4;
    const int lc   = lane & 15;
    const int r0   = blockIdx.x * 64;

    f32x4 acc[4] = {};

    for (int k0 = 0; k0 < 1024; k0 += 128) {
        __syncthreads();
        // stage A tile 64 x 128 f32 -> bf16 (8 float4 per thread, contiguous)
        #pragma unroll
        for (int q = 0; q < 8; ++q) {
            int u   = t * 8 + q;            // 0..2047 float4 units
            int row = u >> 5;               // 32 float4 per row
            int c4  = (u & 31) << 2;
            float4 v = *reinterpret_cast<const float4*>(
                A + (size_t)(r0 + row) * 1024 + k0 + c4);
            ushort4 p;
            p.x = f2bf(v.x); p.y = f2bf(v.y); p.z = f2bf(v.z); p.w = f2bf(v.w);
            *reinterpret_cast<ushort4*>(&As[row][c4]) = p;
        }
        __syncthreads();

        const ushort* arow = &As[16 * w + lc][0];
        #pragma unroll
        for (int h = 0; h < 4; ++h) {
            bf16x8 af = *reinterpret_cast<const bf16x8*>(arow + 32 * h + lg * 8);
            #pragma unroll
            for (int n = 0; n < 4; ++n) {
                bf16x8 bf = *reinterpret_cast<const bf16x8*>(
                    W + (size_t)(16 * n + lc) * 1024 + k0 + 32 * h + lg * 8);
                acc[n] = __builtin_amdgcn_mfma_f32_16x16x32_bf16(af, bf, acc[n], 0, 0, 0);
            }
        }
    }

    if (z != 2) {
        #pragma unroll
        for (int n = 0; n < 4; ++n) {
            float bv = bias[16 * n + lc];
            #pragma unroll
            for (int reg = 0; reg < 4; ++reg) {
                int row = r0 + 16 * w + 4 * lg + reg;
                O[(size_t)row * 64 + 16 * n + lc] = f2bf(acc[n][reg] + bv);
            }
        }
    } else {
        // transposed write: stage output tile [s_local][d] into As, then
        // write vhT[b][d][s] coalesced along s.
        __syncthreads();
        #pragma unroll
        for (int n = 0; n < 4; ++n) {
            float bv = bias[16 * n + lc];
            #pragma unroll
            for (int reg = 0; reg < 4; ++reg)
                As[16 * w + 4 * lg + reg][16 * n + lc] = f2bf(acc[n][reg] + bv);
        }
        __syncthreads();
        const int b  = r0 >> 11;
        const int s0 = r0 & 2047;
        #pragma unroll
        for (int q = 0; q < 2; ++q) {
            int u  = t * 2 + q;
            int d  = u >> 3;
            int s8 = (u & 7) << 3;
            uint4 o;
            uint* ow = reinterpret_cast<uint*>(&o);
            #pragma unroll
            for (int i = 0; i < 4; ++i)
                ow[i] = (uint)As[s8 + 2 * i][d] | ((uint)As[s8 + 2 * i + 1][d] << 16);
            *reinterpret_cast<uint4*>(
                O + (size_t)b * 64 * S_LEN + (size_t)d * S_LEN + s0 + s8) = o;
        }
    }
}

// ---------------------------------------------------------------------------
// Flash attention (MFMA, split-KV): block = 64 q-rows x 256-kv chunk.
// Grid (144, 4).
// ---------------------------------------------------------------------------
__global__ __launch_bounds__(256) void flash_mfma(
    const ushort* __restrict__ qh, const ushort* __restrict__ kh,
    const ushort* __restrict__ vhT,
    float* __restrict__ Opart, float* __restrict__ mpart, float* __restrict__ lpart)
{
    const int b = blockIdx.y;
    const int u = blockIdx.x;
    int gi = 0;
    #pragma unroll
    for (int gg = 0; gg < 7; ++gg)
        if (u >= 2 * (gg + 1) * (gg + 2)) gi = gg + 1;
    const int rem = u - 2 * gi * (gi + 1);
    const int dq  = rem / (gi + 1);
    const int c   = rem - dq * (gi + 1);
    const int qt  = 4 * gi + dq;
    const int r0  = qt * 64;
    const int kvbase = c << 8;
    const int slot = b * 144 + u;

    __shared__ ushort Qs[64][72];
    __shared__ ushort Ks[64][72];
    __shared__ ushort Vt[64][72];
    __shared__ ushort Pw[4][16][72];

    const int t    = threadIdx.x;
    const int w    = t >> 6;
    const int lane = t & 63;
    const int lg   = lane >> 4;
    const int lc   = lane & 15;

    const ushort* qb  = qh  + (size_t)b * S_LEN * 64;
    const ushort* kb  = kh  + (size_t)b * S_LEN * 64;
    const ushort* vtb = vhT + (size_t)b * 64 * S_LEN;

    #pragma unroll
    for (int q = 0; q < 2; ++q) {
        int uu  = t * 2 + q;
        int row = uu >> 3;
        int c8  = (uu & 7) << 3;
        *reinterpret_cast<uint4*>(&Qs[row][c8]) =
            *reinterpret_cast<const uint4*>(qb + (size_t)(r0 + row) * 64 + c8);
    }
    __syncthreads();
    bf16x8 qf0 = *reinterpret_cast<const bf16x8*>(&Qs[16 * w + lc][lg * 8]);
    bf16x8 qf1 = *reinterpret_cast<const bf16x8*>(&Qs[16 * w + lc][32 + lg * 8]);

    f32x4 od[4] = {};
    float m = -INFINITY, lsum = 0.f;
    const int qrow = r0 + 16 * w + lc;

    const int ntt = min(4, ((r0 + 63 - kvbase) >> 6) + 1);
    for (int tt = 0; tt < ntt; ++tt) {
        const int t0 = kvbase + (tt << 6);
        __syncthreads();
        #pragma unroll
        for (int q = 0; q < 2; ++q) {
            int uu  = t * 2 + q;
            int row = uu >> 3;
            int c8  = (uu & 7) << 3;
            *reinterpret_cast<uint4*>(&Ks[row][c8]) =
                *reinterpret_cast<const uint4*>(kb + (size_t)(t0 + row) * 64 + c8);
            *reinterpret_cast<uint4*>(&Vt[row][c8]) =
                *reinterpret_cast<const uint4*>(vtb + (size_t)row * S_LEN + t0 + c8);
        }
        __syncthreads();

        if (t0 <= r0 + 16 * w + 15) {
            f32x4 s[4] = {};
            #pragma unroll
            for (int a = 0; a < 4; ++a) {
                bf16x8 kf0 = *reinterpret_cast<const bf16x8*>(&Ks[16 * a + lc][lg * 8]);
                bf16x8 kf1 = *reinterpret_cast<const bf16x8*>(&Ks[16 * a + lc][32 + lg * 8]);
                s[a] = __builtin_amdgcn_mfma_f32_16x16x32_bf16(kf0, qf0, s[a], 0, 0, 0);
                s[a] = __builtin_amdgcn_mfma_f32_16x16x32_bf16(kf1, qf1, s[a], 0, 0, 0);
            }
            float rm = -1e30f;
            #pragma unroll
            for (int a = 0; a < 4; ++a)
                #pragma unroll
                for (int reg = 0; reg < 4; ++reg) {
                    int kv = t0 + 16 * a + 4 * lg + reg;
                    float v = s[a][reg] * 0.125f;
                    if (kv > qrow) v = -1e30f;
                    s[a][reg] = v;
                    rm = fmaxf(rm, v);
                }
            rm = fmaxf(rm, __shfl_xor(rm, 16));
            rm = fmaxf(rm, __shfl_xor(rm, 32));
            float mn = fmaxf(m, rm);
            float sc = __expf(m - mn);
            float rs = 0.f;
            #pragma unroll
            for (int a = 0; a < 4; ++a)
                #pragma unroll
                for (int reg = 0; reg < 4; ++reg) {
                    float p = __expf(s[a][reg] - mn);
                    s[a][reg] = p;
                    rs += p;
                }
            rs += __shfl_xor(rs, 16);
            rs += __shfl_xor(rs, 32);
            lsum = lsum * sc + rs;
            m = mn;
            #pragma unroll
            for (int di = 0; di < 4; ++di) od[di] *= sc;

            #pragma unroll
            for (int a = 0; a < 4; ++a)
                #pragma unroll
                for (int rp = 0; rp < 2; ++rp) {
                    uint pk = (uint)f2bf(s[a][2 * rp]) |
                              ((uint)f2bf(s[a][2 * rp + 1]) << 16);
                    *reinterpret_cast<uint*>(&Pw[w][lc][16 * a + 4 * lg + 2 * rp]) = pk;
                }
            bf16x8 pf0 = *reinterpret_cast<const bf16x8*>(&Pw[w][lc][lg * 8]);
            bf16x8 pf1 = *reinterpret_cast<const bf16x8*>(&Pw[w][lc][32 + lg * 8]);
            #pragma unroll
            for (int di = 0; di < 4; ++di) {
                bf16x8 vf0 = *reinterpret_cast<const bf16x8*>(&Vt[16 * di + lc][lg * 8]);
                bf16x8 vf1 = *reinterpret_cast<const bf16x8*>(&Vt[16 * di + lc][32 + lg * 8]);
                od[di] = __builtin_amdgcn_mfma_f32_16x16x32_bf16(vf0, pf0, od[di], 0, 0, 0);
                od[di] = __builtin_amdgcn_mfma_f32_16x16x32_bf16(vf1, pf1, od[di], 0, 0, 0);
            }
        }
    }

    #pragma unroll
    for (int di = 0; di < 4; ++di)
        #pragma unroll
        for (int reg = 0; reg < 4; ++reg)
            Opart[(size_t)slot * 4096 + (16 * di + 4 * lg + reg) * 64 + 16 * w + lc] =
                od[di][reg];
    if (lg == 0) {
        mpart[slot * 64 + 16 * w + lc] = m;
        lpart[slot * 64 + 16 * w + lc] = lsum;
    }
}

// ---------------------------------------------------------------------------
// Combine partials -> oh bf16 [8192][64].  Grid (32, 4), 256 threads.
// ---------------------------------------------------------------------------
__global__ __launch_bounds__(256) void flash_combine(
    const float* __restrict__ Opart, const float* __restrict__ mpart,
    const float* __restrict__ lpart, ushort* __restrict__ oh)
{
    const int qt = blockIdx.x, b = blockIdx.y;
    const int gi = qt >> 2;
    const int nc = gi + 1;
    const int ubase = 2 * gi * (gi + 1) + (qt & 3) * (gi + 1);
    __shared__ float T[64][65];

    const int t  = threadIdx.x;
    const int q  = t & 63;
    const int d0 = (t >> 6) << 4;

    float mc[8];
    float M = -INFINITY;
    #pragma unroll
    for (int cc = 0; cc < 8; ++cc) {
        mc[cc] = (cc < nc) ? mpart[(b * 144 + ubase + cc) * 64 + q] : -INFINITY;
        M = fmaxf(M, mc[cc]);
    }
    float L = 0.f;
    float acc[16] = {};
    for (int cc = 0; cc < nc; ++cc) {
        const int slot = b * 144 + ubase + cc;
        float wgt = __expf(mc[cc] - M);
        L += lpart[slot * 64 + q] * wgt;
        const float* op = Opart + (size_t)slot * 4096 + q;
        #pragma unroll
        for (int i = 0; i < 16; ++i)
            acc[i] += wgt * op[(d0 + i) * 64];
    }
    float inv = 1.f / L;
    #pragma unroll
    for (int i = 0; i < 16; ++i) T[q][d0 + i] = acc[i] * inv;
    __syncthreads();

    const int q2 = t >> 2;
    const int ds = (t & 3) << 4;
    uint wbuf[8];
    #pragma unroll
    for (int i = 0; i < 8; ++i)
        wbuf[i] = (uint)f2bf(T[q2][ds + 2 * i]) |
                  ((uint)f2bf(T[q2][ds + 2 * i + 1]) << 16);
    ushort* dst = oh + ((size_t)b * S_LEN + qt * 64 + q2) * 64 + ds;
    uint4 o1, o2;
    o1.x = wbuf[0]; o1.y = wbuf[1]; o1.z = wbuf[2]; o1.w = wbuf[3];
    o2.x = wbuf[4]; o2.y = wbuf[5]; o2.z = wbuf[6]; o2.w = wbuf[7];
    *reinterpret_cast<uint4*>(dst)     = o1;
    *reinterpret_cast<uint4*>(dst + 8) = o2;
}

// ---------------------------------------------------------------------------
// Epilogue (MFMA): out[8192,1024] = oh[8192,64] @ WoT^T.  Grid (128, 8).
// ---------------------------------------------------------------------------
__global__ __launch_bounds__(256) void epilogue_mfma(
    const ushort* __restrict__ oh, const ushort* __restrict__ WoT,
    float* __restrict__ out)
{
    const int r0 = blockIdx.x * 64;
    const int c0 = blockIdx.y * 128;
    __shared__ ushort As[64][72];
    __shared__ ushort Bs[128][72];

    const int t    = threadIdx.x;
    const int w    = t >> 6;
    const int lane = t & 63;
    const int lg   = lane >> 4;
    const int lc   = lane & 15;

    #pragma unroll
    for (int q = 0; q < 2; ++q) {
        int u   = t * 2 + q;
        int row = u >> 3;
        int c8  = (u & 7) << 3;
        *reinterpret_cast<uint4*>(&As[row][c8]) =
            *reinterpret_cast<const uint4*>(oh + (size_t)(r0 + row) * 64 + c8);
    }
    #pragma unroll
    for (int q = 0; q < 4; ++q) {
        int u   = t * 4 + q;
        int row = u >> 3;
        int c8  = (u & 7) << 3;
        *reinterpret_cast<uint4*>(&Bs[row][c8]) =
            *reinterpret_cast<const uint4*>(WoT + (size_t)(c0 + row) * 64 + c8);
    }
    __syncthreads();

    bf16x8 af0 = *reinterpret_cast<const bf16x8*>(&As[16 * w + lc][lg * 8]);
    bf16x8 af1 = *reinterpret_cast<const bf16x8*>(&As[16 * w + lc][32 + lg * 8]);
    f32x4 acc[8] = {};
    #pragma unroll
    for (int n = 0; n < 8; ++n) {
        bf16x8 bf0 = *reinterpret_cast<const bf16x8*>(&Bs[16 * n + lc][lg * 8]);
        bf16x8 bf1 = *reinterpret_cast<const bf16x8*>(&Bs[16 * n + lc][32 + lg * 8]);
        acc[n] = __builtin_amdgcn_mfma_f32_16x16x32_bf16(af0, bf0, acc[n], 0, 0, 0);
        acc[n] = __builtin_amdgcn_mfma_f32_16x16x32_bf16(af1, bf1, acc[n], 0, 0, 0);
    }
    #pragma unroll
    for (int n = 0; n < 8; ++n)
        #pragma unroll
        for (int reg = 0; reg < 4; ++reg)
            out[(size_t)(r0 + 16 * w + 4 * lg + reg) * 1024 + c0 + 16 * n + lc] =
                acc[n][reg];
}

// ---------------------------------------------------------------------------
extern "C" void kernel_launch(void* const* d_in, const int* in_sizes, int n_in,
                              void* d_out, int out_size, void* d_ws, size_t ws_size,
                              hipStream_t stream)
{
    const float* query = (const float*)d_in[0];
    const float* key   = (const float*)d_in[1];
    const float* value = (const float*)d_in[2];
    const float* Wq   = (const float*)d_in[4];
    const float* Wk   = (const float*)d_in[5];
    const float* Wv   = (const float*)d_in[6];
    const float* wq_h = (const float*)d_in[7];
    const float* bq_h = (const float*)d_in[8];
    const float* wk_h = (const float*)d_in[9];
    const float* bk_h = (const float*)d_in[10];
    const float* wv_h = (const float*)d_in[11];
    const float* bv_h = (const float*)d_in[12];
    const float* Wo   = (const float*)d_in[13];
    float* out = (float*)d_out;

    // workspace (ushort units): ~5.6 MB
    ushort* W16  = (ushort*)d_ws;
    ushort* WT0  = W16;                 // 64*1024 each
    ushort* WT1  = W16 + 65536;
    ushort* WT2  = W16 + 131072;
    ushort* WoT  = W16 + 196608;        // 1024*64
    ushort* qh   = W16 + 262144;        // 8192*64 each
    ushort* kh   = qh + 524288;
    ushort* vhT  = kh + 524288;         // [b][64][2048] (written by proj z==2)
    ushort* oh   = vhT + 524288;
    ushort* whT0 = oh + 524288;         // 64*1024 each
    ushort* whT1 = whT0 + 65536;
    ushort* whT2 = whT1 + 65536;

    // flash partials in d_out (9.7 MB < 33.5 MB); epilogue rewrites all of it.
    float* Opart = out;                 // 576 * 4096
    float* mpart = out + 2359296;       // 576 * 64
    float* lpart = out + 2396160;

    transpose_wh<<<dim3(16, 3), 256, 0, stream>>>(
        wq_h, wk_h, wv_h, whT0, whT1, whT2);
    fold_wo<<<256, 256, 0, stream>>>(Wo, WoT);

    prep_direct<<<dim3(64, 3), 256, 0, stream>>>(
        Wq, Wk, Wv, whT0, whT1, whT2, WT0, WT1, WT2);

    proj_mfma<<<dim3(NROWS / 64, 3), 256, 0, stream>>>(
        query, key, value, WT0, WT1, WT2, bq_h, bk_h, bv_h, qh, kh, vhT);

    flash_mfma<<<dim3(144, BATCH), 256, 0, stream>>>(
        qh, kh, vhT, Opart, mpart, lpart);
    flash_combine<<<dim3(S_LEN / 64, BATCH), 256, 0, stream>>>(
        Opart, mpart, lpart, oh);

    epilogue_mfma<<<dim3(NROWS / 64, DMODEL / 128), 256, 0, stream>>>(oh, WoT, out);
}

// Round 18
// 72.289 us; speedup vs baseline: 1.2902x; 1.2902x over previous
//
#include <hip/hip_runtime.h>
#include <math.h>

#define S_LEN 2048
#define BATCH 4
#define DMODEL 1024
#define HDIM 64
#define NROWS (BATCH * S_LEN)   // 8192

typedef __attribute__((ext_vector_type(8))) short bf16x8;
typedef __attribute__((ext_vector_type(4))) float f32x4;

__device__ inline ushort f2bf(float f) {
    union { float f; uint u; } v{f};
    uint r = v.u + 0x7fffu + ((v.u >> 16) & 1u);   // RNE
    return (ushort)(r >> 16);
}

__device__ inline bf16x8 cvt8(float4 a, float4 b) {
    bf16x8 r;
    r[0] = (short)f2bf(a.x); r[1] = (short)f2bf(a.y);
    r[2] = (short)f2bf(a.z); r[3] = (short)f2bf(a.w);
    r[4] = (short)f2bf(b.x); r[5] = (short)f2bf(b.y);
    r[6] = (short)f2bf(b.z); r[7] = (short)f2bf(b.w);
    return r;
}

// ---------------------------------------------------------------------------
// transpose_wh: w_h f32 [1024][64] -> whT bf16 [64][1024].  Grid (16, 3).
// ---------------------------------------------------------------------------
__global__ __launch_bounds__(256) void transpose_wh(
    const float* __restrict__ B0, const float* __restrict__ B1, const float* __restrict__ B2,
    ushort* __restrict__ T0, ushort* __restrict__ T1, ushort* __restrict__ T2)
{
    const int z = blockIdx.y;
    const float* B = (z == 0) ? B0 : (z == 1) ? B1 : B2;
    ushort* T      = (z == 0) ? T0 : (z == 1) ? T1 : T2;
    const int kr0 = blockIdx.x * 64;
    __shared__ ushort Ts[64][72];
    const int t = threadIdx.x;

    #pragma unroll
    for (int q = 0; q < 4; ++q) {
        int u   = t * 4 + q;
        int row = u >> 4;
        int c4  = (u & 15) << 2;
        float4 v = *reinterpret_cast<const float4*>(
            B + (size_t)(kr0 + row) * 64 + c4);
        Ts[row][c4 + 0] = f2bf(v.x); Ts[row][c4 + 1] = f2bf(v.y);
        Ts[row][c4 + 2] = f2bf(v.z); Ts[row][c4 + 3] = f2bf(v.w);
    }
    __syncthreads();
    #pragma unroll
    for (int q = 0; q < 2; ++q) {
        int u  = t * 2 + q;
        int h  = u >> 3;
        int k8 = (u & 7) << 3;
        uint4 o;
        uint* ow = reinterpret_cast<uint*>(&o);
        #pragma unroll
        for (int i = 0; i < 4; ++i)
            ow[i] = (uint)Ts[k8 + 2 * i][h] | ((uint)Ts[k8 + 2 * i + 1][h] << 16);
        *reinterpret_cast<uint4*>(T + (size_t)h * 1024 + kr0 + k8) = o;
    }
}

// ---------------------------------------------------------------------------
// fold_wo: WoT[e][j] = sum_h Wo[h*64+j][e]  -> bf16 [1024][64].  Grid 256.
// ---------------------------------------------------------------------------
__global__ __launch_bounds__(256) void fold_wo(const float* __restrict__ Wo,
                                               ushort* __restrict__ WoT)
{
    int idx = blockIdx.x * 256 + threadIdx.x;
    int j = idx >> 10;
    int e = idx & 1023;
    float s = 0.f;
    #pragma unroll
    for (int h = 0; h < 16; ++h)
        s += Wo[(size_t)((h << 6) + j) * 1024 + e];
    WoT[(size_t)e * 64 + j] = f2bf(s);
}

// ---------------------------------------------------------------------------
// prep_direct: WeffT_z[h][d] = (W_z @ w_h_z)^T bf16.  Grid (64, 3).
// ---------------------------------------------------------------------------
__global__ __launch_bounds__(256) void prep_direct(
    const float* __restrict__ A0, const float* __restrict__ A1, const float* __restrict__ A2,
    const ushort* __restrict__ W0, const ushort* __restrict__ W1, const ushort* __restrict__ W2,
    ushort* __restrict__ T0, ushort* __restrict__ T1, ushort* __restrict__ T2)
{
    const int z = blockIdx.y;
    const float* A  = (z == 0) ? A0 : (z == 1) ? A1 : A2;
    const ushort* W = (z == 0) ? W0 : (z == 1) ? W1 : W2;
    ushort* T       = (z == 0) ? T0 : (z == 1) ? T1 : T2;

    __shared__ float Pr[4][16][64];

    const int t    = threadIdx.x;
    const int w    = t >> 6;
    const int lane = t & 63;
    const int lg   = lane >> 4;
    const int lc   = lane & 15;
    const int r0   = blockIdx.x * 16;

    const float*  Ap = A + (size_t)(r0 + lc) * 1024 + (w << 8) + (lg << 3);
    const ushort* Bp = W + (size_t)lc * 1024 + (w << 8) + (lg << 3);

    f32x4 acc[4] = {};
    float4 a0[2], a1[2];
    uint4  bl[2][4];

    #pragma unroll
    for (int d = 0; d < 2; ++d) {
        a0[d] = *reinterpret_cast<const float4*>(Ap + d * 32);
        a1[d] = *reinterpret_cast<const float4*>(Ap + d * 32 + 4);
        #pragma unroll
        for (int n = 0; n < 4; ++n)
            bl[d][n] = *reinterpret_cast<const uint4*>(Bp + n * 16384 + d * 32);
    }

    #pragma unroll
    for (int ks = 0; ks < 8; ++ks) {
        const int d = ks & 1;
        bf16x8 af = cvt8(a0[d], a1[d]);
        bf16x8 bfr[4];
        #pragma unroll
        for (int n = 0; n < 4; ++n)
            bfr[n] = __builtin_bit_cast(bf16x8, bl[d][n]);
        if (ks < 6) {
            a0[d] = *reinterpret_cast<const float4*>(Ap + (ks + 2) * 32);
            a1[d] = *reinterpret_cast<const float4*>(Ap + (ks + 2) * 32 + 4);
            #pragma unroll
            for (int n = 0; n < 4; ++n)
                bl[d][n] = *reinterpret_cast<const uint4*>(Bp + n * 16384 + (ks + 2) * 32);
        }
        #pragma unroll
        for (int n = 0; n < 4; ++n)
            acc[n] = __builtin_amdgcn_mfma_f32_16x16x32_bf16(af, bfr[n], acc[n], 0, 0, 0);
    }

    #pragma unroll
    for (int n = 0; n < 4; ++n)
        #pragma unroll
        for (int reg = 0; reg < 4; ++reg)
            Pr[w][4 * lg + reg][16 * n + lc] = acc[n][reg];
    __syncthreads();

    const int row = t >> 4;
    const int col = (t & 15) << 2;
    float s[4];
    #pragma unroll
    for (int i = 0; i < 4; ++i)
        s[i] = Pr[0][row][col + i] + Pr[1][row][col + i] +
               Pr[2][row][col + i] + Pr[3][row][col + i];
    #pragma unroll
    for (int i = 0; i < 4; ++i)
        T[(size_t)(col + i) * 1024 + r0 + row] = f2bf(s[i]);
}

// ---------------------------------------------------------------------------
// Projections (MFMA): Grid (128, 3), 256 thr = 4 waves.  Best-measured proj
// structure (R4/R12/R13/R16; 11 variants all >= this).  z==0/1 write qh/kh
// row-major; z==2 writes vhT transposed directly — no transpose_v kernel.
// ---------------------------------------------------------------------------
__global__ __launch_bounds__(256) void proj_mfma(
    const float* __restrict__ A0, const float* __restrict__ A1, const float* __restrict__ A2,
    const ushort* __restrict__ W0, const ushort* __restrict__ W1, const ushort* __restrict__ W2,
    const float* __restrict__ b0, const float* __restrict__ b1, const float* __restrict__ b2,
    ushort* __restrict__ O0, ushort* __restrict__ O1, ushort* __restrict__ O2)
{
    const int z = blockIdx.y;
    const float* A  = (z == 0) ? A0 : (z == 1) ? A1 : A2;
    const ushort* W = (z == 0) ? W0 : (z == 1) ? W1 : W2;
    const float* bias = (z == 0) ? b0 : (z == 1) ? b1 : b2;
    ushort* O       = (z == 0) ? O0 : (z == 1) ? O1 : O2;

    __shared__ ushort As[64][72];
    __shared__ ushort Bs[64][72];

    const int t    = threadIdx.x;
    const int w    = t >> 6;
    const int lane = t & 63;
    const int lg   = lane >> 4;
    const int lc   = lane & 15;
    const int r0   = blockIdx.x * 64;

    f32x4 acc[4] = {};

    for (int k0 = 0; k0 < 1024; k0 += 64) {
        __syncthreads();
        #pragma unroll
        for (int q = 0; q < 4; ++q) {
            int u   = t * 4 + q;
            int row = u >> 4;
            int c4  = (u & 15) << 2;
            float4 v = *reinterpret_cast<const float4*>(
                A + (size_t)(r0 + row) * 1024 + k0 + c4);
            ushort4 p;
            p.x = f2bf(v.x); p.y = f2bf(v.y); p.z = f2bf(v.z); p.w = f2bf(v.w);
            *reinterpret_cast<ushort4*>(&As[row][c4]) = p;
        }
        #pragma unroll
        for (int q = 0; q < 2; ++q) {
            int u   = t * 2 + q;
            int row = u >> 3;
            int c8  = (u & 7) << 3;
            uint4 v = *reinterpret_cast<const uint4*>(W + (size_t)row * 1024 + k0 + c8);
            *reinterpret_cast<uint4*>(&Bs[row][c8]) = v;
        }
        __syncthreads();

        bf16x8 af0 = *reinterpret_cast<const bf16x8*>(&As[16 * w + lc][lg * 8]);
        bf16x8 af1 = *reinterpret_cast<const bf16x8*>(&As[16 * w + lc][32 + lg * 8]);
        #pragma unroll
        for (int n = 0; n < 4; ++n) {
            bf16x8 bf0 = *reinterpret_cast<const bf16x8*>(&Bs[16 * n + lc][lg * 8]);
            bf16x8 bf1 = *reinterpret_cast<const bf16x8*>(&Bs[16 * n + lc][32 + lg * 8]);
            acc[n] = __builtin_amdgcn_mfma_f32_16x16x32_bf16(af0, bf0, acc[n], 0, 0, 0);
            acc[n] = __builtin_amdgcn_mfma_f32_16x16x32_bf16(af1, bf1, acc[n], 0, 0, 0);
        }
    }

    if (z != 2) {
        #pragma unroll
        for (int n = 0; n < 4; ++n) {
            float bv = bias[16 * n + lc];
            #pragma unroll
            for (int reg = 0; reg < 4; ++reg) {
                int row = r0 + 16 * w + 4 * lg + reg;
                O[(size_t)row * 64 + 16 * n + lc] = f2bf(acc[n][reg] + bv);
            }
        }
    } else {
        // transposed write: stage output tile [s_local][d] into As, then
        // write vhT[b][d][s] coalesced along s.
        __syncthreads();
        #pragma unroll
        for (int n = 0; n < 4; ++n) {
            float bv = bias[16 * n + lc];
            #pragma unroll
            for (int reg = 0; reg < 4; ++reg)
                As[16 * w + 4 * lg + reg][16 * n + lc] = f2bf(acc[n][reg] + bv);
        }
        __syncthreads();
        const int b  = r0 >> 11;
        const int s0 = r0 & 2047;
        #pragma unroll
        for (int q = 0; q < 2; ++q) {
            int u  = t * 2 + q;
            int d  = u >> 3;
            int s8 = (u & 7) << 3;
            uint4 o;
            uint* ow = reinterpret_cast<uint*>(&o);
            #pragma unroll
            for (int i = 0; i < 4; ++i)
                ow[i] = (uint)As[s8 + 2 * i][d] | ((uint)As[s8 + 2 * i + 1][d] << 16);
            *reinterpret_cast<uint4*>(
                O + (size_t)b * 64 * S_LEN + (size_t)d * S_LEN + s0 + s8) = o;
        }
    }
}

// ---------------------------------------------------------------------------
// Flash attention (MFMA, split-KV): block = 64 q-rows x 256-kv chunk.
// Grid (144, 4).
// ---------------------------------------------------------------------------
__global__ __launch_bounds__(256) void flash_mfma(
    const ushort* __restrict__ qh, const ushort* __restrict__ kh,
    const ushort* __restrict__ vhT,
    float* __restrict__ Opart, float* __restrict__ mpart, float* __restrict__ lpart)
{
    const int b = blockIdx.y;
    const int u = blockIdx.x;
    int gi = 0;
    #pragma unroll
    for (int gg = 0; gg < 7; ++gg)
        if (u >= 2 * (gg + 1) * (gg + 2)) gi = gg + 1;
    const int rem = u - 2 * gi * (gi + 1);
    const int dq  = rem / (gi + 1);
    const int c   = rem - dq * (gi + 1);
    const int qt  = 4 * gi + dq;
    const int r0  = qt * 64;
    const int kvbase = c << 8;
    const int slot = b * 144 + u;

    __shared__ ushort Qs[64][72];
    __shared__ ushort Ks[64][72];
    __shared__ ushort Vt[64][72];
    __shared__ ushort Pw[4][16][72];

    const int t    = threadIdx.x;
    const int w    = t >> 6;
    const int lane = t & 63;
    const int lg   = lane >> 4;
    const int lc   = lane & 15;

    const ushort* qb  = qh  + (size_t)b * S_LEN * 64;
    const ushort* kb  = kh  + (size_t)b * S_LEN * 64;
    const ushort* vtb = vhT + (size_t)b * 64 * S_LEN;

    #pragma unroll
    for (int q = 0; q < 2; ++q) {
        int uu  = t * 2 + q;
        int row = uu >> 3;
        int c8  = (uu & 7) << 3;
        *reinterpret_cast<uint4*>(&Qs[row][c8]) =
            *reinterpret_cast<const uint4*>(qb + (size_t)(r0 + row) * 64 + c8);
    }
    __syncthreads();
    bf16x8 qf0 = *reinterpret_cast<const bf16x8*>(&Qs[16 * w + lc][lg * 8]);
    bf16x8 qf1 = *reinterpret_cast<const bf16x8*>(&Qs[16 * w + lc][32 + lg * 8]);

    f32x4 od[4] = {};
    float m = -INFINITY, lsum = 0.f;
    const int qrow = r0 + 16 * w + lc;

    const int ntt = min(4, ((r0 + 63 - kvbase) >> 6) + 1);
    for (int tt = 0; tt < ntt; ++tt) {
        const int t0 = kvbase + (tt << 6);
        __syncthreads();
        #pragma unroll
        for (int q = 0; q < 2; ++q) {
            int uu  = t * 2 + q;
            int row = uu >> 3;
            int c8  = (uu & 7) << 3;
            *reinterpret_cast<uint4*>(&Ks[row][c8]) =
                *reinterpret_cast<const uint4*>(kb + (size_t)(t0 + row) * 64 + c8);
            *reinterpret_cast<uint4*>(&Vt[row][c8]) =
                *reinterpret_cast<const uint4*>(vtb + (size_t)row * S_LEN + t0 + c8);
        }
        __syncthreads();

        if (t0 <= r0 + 16 * w + 15) {
            f32x4 s[4] = {};
            #pragma unroll
            for (int a = 0; a < 4; ++a) {
                bf16x8 kf0 = *reinterpret_cast<const bf16x8*>(&Ks[16 * a + lc][lg * 8]);
                bf16x8 kf1 = *reinterpret_cast<const bf16x8*>(&Ks[16 * a + lc][32 + lg * 8]);
                s[a] = __builtin_amdgcn_mfma_f32_16x16x32_bf16(kf0, qf0, s[a], 0, 0, 0);
                s[a] = __builtin_amdgcn_mfma_f32_16x16x32_bf16(kf1, qf1, s[a], 0, 0, 0);
            }
            float rm = -1e30f;
            #pragma unroll
            for (int a = 0; a < 4; ++a)
                #pragma unroll
                for (int reg = 0; reg < 4; ++reg) {
                    int kv = t0 + 16 * a + 4 * lg + reg;
                    float v = s[a][reg] * 0.125f;
                    if (kv > qrow) v = -1e30f;
                    s[a][reg] = v;
                    rm = fmaxf(rm, v);
                }
            rm = fmaxf(rm, __shfl_xor(rm, 16));
            rm = fmaxf(rm, __shfl_xor(rm, 32));
            float mn = fmaxf(m, rm);
            float sc = __expf(m - mn);
            float rs = 0.f;
            #pragma unroll
            for (int a = 0; a < 4; ++a)
                #pragma unroll
                for (int reg = 0; reg < 4; ++reg) {
                    float p = __expf(s[a][reg] - mn);
                    s[a][reg] = p;
                    rs += p;
                }
            rs += __shfl_xor(rs, 16);
            rs += __shfl_xor(rs, 32);
            lsum = lsum * sc + rs;
            m = mn;
            #pragma unroll
            for (int di = 0; di < 4; ++di) od[di] *= sc;

            #pragma unroll
            for (int a = 0; a < 4; ++a)
                #pragma unroll
                for (int rp = 0; rp < 2; ++rp) {
                    uint pk = (uint)f2bf(s[a][2 * rp]) |
                              ((uint)f2bf(s[a][2 * rp + 1]) << 16);
                    *reinterpret_cast<uint*>(&Pw[w][lc][16 * a + 4 * lg + 2 * rp]) = pk;
                }
            bf16x8 pf0 = *reinterpret_cast<const bf16x8*>(&Pw[w][lc][lg * 8]);
            bf16x8 pf1 = *reinterpret_cast<const bf16x8*>(&Pw[w][lc][32 + lg * 8]);
            #pragma unroll
            for (int di = 0; di < 4; ++di) {
                bf16x8 vf0 = *reinterpret_cast<const bf16x8*>(&Vt[16 * di + lc][lg * 8]);
                bf16x8 vf1 = *reinterpret_cast<const bf16x8*>(&Vt[16 * di + lc][32 + lg * 8]);
                od[di] = __builtin_amdgcn_mfma_f32_16x16x32_bf16(vf0, pf0, od[di], 0, 0, 0);
                od[di] = __builtin_amdgcn_mfma_f32_16x16x32_bf16(vf1, pf1, od[di], 0, 0, 0);
            }
        }
    }

    #pragma unroll
    for (int di = 0; di < 4; ++di)
        #pragma unroll
        for (int reg = 0; reg < 4; ++reg)
            Opart[(size_t)slot * 4096 + (16 * di + 4 * lg + reg) * 64 + 16 * w + lc] =
                od[di][reg];
    if (lg == 0) {
        mpart[slot * 64 + 16 * w + lc] = m;
        lpart[slot * 64 + 16 * w + lc] = lsum;
    }
}

// ---------------------------------------------------------------------------
// Combine partials -> oh bf16 [8192][64].  Grid (32, 4), 256 threads.
// ---------------------------------------------------------------------------
__global__ __launch_bounds__(256) void flash_combine(
    const float* __restrict__ Opart, const float* __restrict__ mpart,
    const float* __restrict__ lpart, ushort* __restrict__ oh)
{
    const int qt = blockIdx.x, b = blockIdx.y;
    const int gi = qt >> 2;
    const int nc = gi + 1;
    const int ubase = 2 * gi * (gi + 1) + (qt & 3) * (gi + 1);
    __shared__ float T[64][65];

    const int t  = threadIdx.x;
    const int q  = t & 63;
    const int d0 = (t >> 6) << 4;

    float mc[8];
    float M = -INFINITY;
    #pragma unroll
    for (int cc = 0; cc < 8; ++cc) {
        mc[cc] = (cc < nc) ? mpart[(b * 144 + ubase + cc) * 64 + q] : -INFINITY;
        M = fmaxf(M, mc[cc]);
    }
    float L = 0.f;
    float acc[16] = {};
    for (int cc = 0; cc < nc; ++cc) {
        const int slot = b * 144 + ubase + cc;
        float wgt = __expf(mc[cc] - M);
        L += lpart[slot * 64 + q] * wgt;
        const float* op = Opart + (size_t)slot * 4096 + q;
        #pragma unroll
        for (int i = 0; i < 16; ++i)
            acc[i] += wgt * op[(d0 + i) * 64];
    }
    float inv = 1.f / L;
    #pragma unroll
    for (int i = 0; i < 16; ++i) T[q][d0 + i] = acc[i] * inv;
    __syncthreads();

    const int q2 = t >> 2;
    const int ds = (t & 3) << 4;
    uint wbuf[8];
    #pragma unroll
    for (int i = 0; i < 8; ++i)
        wbuf[i] = (uint)f2bf(T[q2][ds + 2 * i]) |
                  ((uint)f2bf(T[q2][ds + 2 * i + 1]) << 16);
    ushort* dst = oh + ((size_t)b * S_LEN + qt * 64 + q2) * 64 + ds;
    uint4 o1, o2;
    o1.x = wbuf[0]; o1.y = wbuf[1]; o1.z = wbuf[2]; o1.w = wbuf[3];
    o2.x = wbuf[4]; o2.y = wbuf[5]; o2.z = wbuf[6]; o2.w = wbuf[7];
    *reinterpret_cast<uint4*>(dst)     = o1;
    *reinterpret_cast<uint4*>(dst + 8) = o2;
}

// ---------------------------------------------------------------------------
// Epilogue (MFMA): out[8192,1024] = oh[8192,64] @ WoT^T.  Grid (128, 8).
// ---------------------------------------------------------------------------
__global__ __launch_bounds__(256) void epilogue_mfma(
    const ushort* __restrict__ oh, const ushort* __restrict__ WoT,
    float* __restrict__ out)
{
    const int r0 = blockIdx.x * 64;
    const int c0 = blockIdx.y * 128;
    __shared__ ushort As[64][72];
    __shared__ ushort Bs[128][72];

    const int t    = threadIdx.x;
    const int w    = t >> 6;
    const int lane = t & 63;
    const int lg   = lane >> 4;
    const int lc   = lane & 15;

    #pragma unroll
    for (int q = 0; q < 2; ++q) {
        int u   = t * 2 + q;
        int row = u >> 3;
        int c8  = (u & 7) << 3;
        *reinterpret_cast<uint4*>(&As[row][c8]) =
            *reinterpret_cast<const uint4*>(oh + (size_t)(r0 + row) * 64 + c8);
    }
    #pragma unroll
    for (int q = 0; q < 4; ++q) {
        int u   = t * 4 + q;
        int row = u >> 3;
        int c8  = (u & 7) << 3;
        *reinterpret_cast<uint4*>(&Bs[row][c8]) =
            *reinterpret_cast<const uint4*>(WoT + (size_t)(c0 + row) * 64 + c8);
    }
    __syncthreads();

    bf16x8 af0 = *reinterpret_cast<const bf16x8*>(&As[16 * w + lc][lg * 8]);
    bf16x8 af1 = *reinterpret_cast<const bf16x8*>(&As[16 * w + lc][32 + lg * 8]);
    f32x4 acc[8] = {};
    #pragma unroll
    for (int n = 0; n < 8; ++n) {
        bf16x8 bf0 = *reinterpret_cast<const bf16x8*>(&Bs[16 * n + lc][lg * 8]);
        bf16x8 bf1 = *reinterpret_cast<const bf16x8*>(&Bs[16 * n + lc][32 + lg * 8]);
        acc[n] = __builtin_amdgcn_mfma_f32_16x16x32_bf16(af0, bf0, acc[n], 0, 0, 0);
        acc[n] = __builtin_amdgcn_mfma_f32_16x16x32_bf16(af1, bf1, acc[n], 0, 0, 0);
    }
    #pragma unroll
    for (int n = 0; n < 8; ++n)
        #pragma unroll
        for (int reg = 0; reg < 4; ++reg)
            out[(size_t)(r0 + 16 * w + 4 * lg + reg) * 1024 + c0 + 16 * n + lc] =
                acc[n][reg];
}

// ---------------------------------------------------------------------------
extern "C" void kernel_launch(void* const* d_in, const int* in_sizes, int n_in,
                              void* d_out, int out_size, void* d_ws, size_t ws_size,
                              hipStream_t stream)
{
    const float* query = (const float*)d_in[0];
    const float* key   = (const float*)d_in[1];
    const float* value = (const float*)d_in[2];
    const float* Wq   = (const float*)d_in[4];
    const float* Wk   = (const float*)d_in[5];
    const float* Wv   = (const float*)d_in[6];
    const float* wq_h = (const float*)d_in[7];
    const float* bq_h = (const float*)d_in[8];
    const float* wk_h = (const float*)d_in[9];
    const float* bk_h = (const float*)d_in[10];
    const float* wv_h = (const float*)d_in[11];
    const float* bv_h = (const float*)d_in[12];
    const float* Wo   = (const float*)d_in[13];
    float* out = (float*)d_out;

    // workspace (ushort units): ~5.6 MB
    ushort* W16  = (ushort*)d_ws;
    ushort* WT0  = W16;                 // 64*1024 each
    ushort* WT1  = W16 + 65536;
    ushort* WT2  = W16 + 131072;
    ushort* WoT  = W16 + 196608;        // 1024*64
    ushort* qh   = W16 + 262144;        // 8192*64 each
    ushort* kh   = qh + 524288;
    ushort* vhT  = kh + 524288;         // [b][64][2048] (written by proj z==2)
    ushort* oh   = vhT + 524288;
    ushort* whT0 = oh + 524288;         // 64*1024 each
    ushort* whT1 = whT0 + 65536;
    ushort* whT2 = whT1 + 65536;

    // flash partials in d_out (9.7 MB < 33.5 MB); epilogue rewrites all of it.
    float* Opart = out;                 // 576 * 4096
    float* mpart = out + 2359296;       // 576 * 64
    float* lpart = out + 2396160;

    transpose_wh<<<dim3(16, 3), 256, 0, stream>>>(
        wq_h, wk_h, wv_h, whT0, whT1, whT2);
    fold_wo<<<256, 256, 0, stream>>>(Wo, WoT);

    prep_direct<<<dim3(64, 3), 256, 0, stream>>>(
        Wq, Wk, Wv, whT0, whT1, whT2, WT0, WT1, WT2);

    proj_mfma<<<dim3(NROWS / 64, 3), 256, 0, stream>>>(
        query, key, value, WT0, WT1, WT2, bq_h, bk_h, bv_h, qh, kh, vhT);

    flash_mfma<<<dim3(144, BATCH), 256, 0, stream>>>(
        qh, kh, vhT, Opart, mpart, lpart);
    flash_combine<<<dim3(S_LEN / 64, BATCH), 256, 0, stream>>>(
        Opart, mpart, lpart, oh);

    epilogue_mfma<<<dim3(NROWS / 64, DMODEL / 128), 256, 0, stream>>>(oh, WoT, out);
}